// Round 3
// baseline (489.599 us; speedup 1.0000x reference)
//
#include <hip/hip_runtime.h>
#include <cstdint>

#define NEXP 8
#define TOPK 2
#define NTOK 4096
#define NSLOT (NTOK * TOPK)   // 8192
#define CAP 1280              // expert capacity
#define DM 2048               // d_model == hidden
#define EC (NEXP * CAP)       // 10240 binned rows
#define KT 32                 // K tiles: 2048 / 64

typedef __bf16 bf16x8 __attribute__((ext_vector_type(8)));
typedef __bf16 bf16x4 __attribute__((ext_vector_type(4)));
typedef float  f32x4  __attribute__((ext_vector_type(4)));

typedef const void __attribute__((address_space(1))) gvoid;
typedef void __attribute__((address_space(3))) lvoid;

__device__ __forceinline__ void gld16(const void* g, void* l) {
  __builtin_amdgcn_global_load_lds((gvoid*)(uintptr_t)g, (lvoid*)(uintptr_t)l,
                                   16, 0, 0);
}

// ---------------------------------------------------------------- routing
__global__ void route_k(const int* __restrict__ eidx, int* __restrict__ row_token,
                        int* __restrict__ slot_dest, int* __restrict__ mcount,
                        float* __restrict__ out) {
  __shared__ int lh[256][NEXP];
  int tid = threadIdx.x;
  for (int i = tid; i < EC; i += 256) row_token[i] = -1;
#pragma unroll
  for (int e = 0; e < NEXP; ++e) lh[tid][e] = 0;
  __syncthreads();
  int base = tid * 32;
  for (int j = 0; j < 32; ++j) lh[tid][eidx[base + j]]++;
  __syncthreads();
  if (tid < NEXP) {
    int run = 0;
    for (int i = 0; i < 256; ++i) { int t = lh[i][tid]; lh[i][tid] = run; run += t; }
    mcount[tid] = run < CAP ? run : CAP;
    out[(size_t)NTOK * DM + tid] = (float)run;
  }
  __syncthreads();
  for (int j = 0; j < 32; ++j) {
    int t = base + j;
    int e = eidx[t];
    int r = lh[tid][e]++;
    if (r < CAP) { int dst = e * CAP + r; slot_dest[t] = dst; row_token[dst] = t >> 1; }
    else slot_dest[t] = -1;
  }
}

// ------------------------------------------------------- gather + fp32->bf16
__global__ void gather_k(const float* __restrict__ x, const int* __restrict__ row_token,
                         __bf16* __restrict__ xg) {
  int r = blockIdx.x;
  int c = threadIdx.x * 8;
  int tok = row_token[r];
  bf16x8 o;
  if (tok >= 0) {
    const float* src = x + (size_t)tok * DM + c;
    float4 a = *(const float4*)src;
    float4 b = *(const float4*)(src + 4);
    o[0] = (__bf16)a.x; o[1] = (__bf16)a.y; o[2] = (__bf16)a.z; o[3] = (__bf16)a.w;
    o[4] = (__bf16)b.x; o[5] = (__bf16)b.y; o[6] = (__bf16)b.z; o[7] = (__bf16)b.w;
  } else {
#pragma unroll
    for (int j = 0; j < 8; ++j) o[j] = (__bf16)0.f;
  }
  *(bf16x8*)(xg + (size_t)r * DM + c) = o;
}

// --------------------------------------- fp32 [E][K][N] -> bf16 [E][N][K]
__global__ void transT_k(const float* __restrict__ w, __bf16* __restrict__ wT) {
  __shared__ __bf16 t[64][65];
  int e = blockIdx.z;
  int n0 = blockIdx.x * 64, k0 = blockIdx.y * 64;
  const float* src = w + ((size_t)e << 22) + (size_t)k0 * DM + n0;
  __bf16* dst = wT + ((size_t)e << 22) + (size_t)n0 * DM + k0;
  int c = threadIdx.x & 63, r4 = threadIdx.x >> 6;
#pragma unroll
  for (int p = 0; p < 16; ++p) {
    int r = p * 4 + r4;
    t[r][c] = (__bf16)src[(size_t)r * DM + c];
  }
  __syncthreads();
  int j = threadIdx.x & 15, rr0 = threadIdx.x >> 4;
#pragma unroll
  for (int q = 0; q < 4; ++q) {
    int rr = q * 16 + rr0;
    bf16x4 v;
    v[0] = t[4 * j + 0][rr];
    v[1] = t[4 * j + 1][rr];
    v[2] = t[4 * j + 2][rr];
    v[3] = t[4 * j + 3][rr];
    *(bf16x4*)(dst + (size_t)rr * DM + 4 * j) = v;
  }
}

// ------------------------------------------------------------------- GEMM
// C[rows,N] = A[rows,K] * BT[N,K]^T per expert. BM=128, BN=256, BK=64.
// 512 thr = 8 waves (2M x 4N), per-wave 64x64 C, acc[4][4].
// Pipeline invariant (distance-2, same-parity buffer reuse, 2 bufs):
//   tile t lives in buf d=t&1.  Per tile:
//     [vmcnt(6); s_barrier]            -- t's 6 loads (issued at t-2) landed;
//                                         t+1's 6 remain in flight (never 0)
//     issue 16 ds_read_b128 (kk0 frags first, then kk1)
//     MFMA x16 on kk0                  -- compiler waits lgkmcnt(8): kk1 reads
//                                         overlap kk0 compute
//     [lgkmcnt(0); s_barrier]          -- ALL waves captured tile t to regs
//                                         => buf d is free
//     stage tile t+2 -> buf d (6 x global_load_lds, 16B/lane)
//     MFMA x16 on kk1
// LDS rows 128B, chunk ^= (row&7): 0 bank conflicts (R1-proven); staged with
// inverse-swizzled GLOBAL source + linear LDS dest (rule #21).
template<bool SWI>
__global__ __launch_bounds__(512, 2)
void gemm8_k(const __bf16* __restrict__ A0, const __bf16* __restrict__ BT,
             __bf16* C, __bf16* U, const int* __restrict__ mcount) {
  int e = blockIdx.z, mt = blockIdx.y, nt = blockIdx.x;
  if (mt * 128 >= mcount[e]) return;

  __shared__ __align__(16) char smem[96 * 1024];
  char* lA = smem;                    // 2 x 16KB (128 rows x 128B)
  char* lB = smem + 32768;            // 2 x 32KB (256 rows x 128B)

  int tid = threadIdx.x, w = tid >> 6, l = tid & 63;
  int wr = w >> 2, wc = w & 3;
  int lr = l & 15, kg = l >> 4;

  const char* gA = (const char*)(A0 + (size_t)(e * CAP + mt * 128) * DM);
  const char* gB = (const char*)(BT + ((size_t)e * DM + (size_t)nt * 256) * DM);

  int sr = tid >> 3;                  // stage row-in-call (uses full tid)
  int scs = (tid & 7) ^ (sr & 7);     // inverse-swizzled source chunk

  // one call: 512 lanes x 16B = 64 rows x 128B, LDS linear
  auto stageA = [&](int t, int d, int s) {
    gld16(gA + (size_t)(s * 64 + sr) * 4096 + (size_t)t * 128 + scs * 16,
          lA + d * 16384 + s * 8192 + w * 1024);
  };
  auto stageB = [&](int t, int d, int s) {
    gld16(gB + (size_t)(s * 64 + sr) * 4096 + (size_t)t * 128 + scs * 16,
          lB + d * 32768 + s * 8192 + w * 1024);
  };

  // prologue: tile 0 -> buf0 (6 loads), tile 1 -> buf1 (6 loads)
  stageA(0, 0, 0); stageA(0, 0, 1);
  stageB(0, 0, 0); stageB(0, 0, 1); stageB(0, 0, 2); stageB(0, 0, 3);
  stageA(1, 1, 0); stageA(1, 1, 1);
  stageB(1, 1, 0); stageB(1, 1, 1); stageB(1, 1, 2); stageB(1, 1, 3);

  f32x4 acc[4][4];
#pragma unroll
  for (int m = 0; m < 4; ++m)
#pragma unroll
    for (int n = 0; n < 4; ++n)
#pragma unroll
      for (int j = 0; j < 4; ++j) acc[m][n][j] = 0.f;

#pragma unroll 1
  for (int t = 0; t < KT; ++t) {
    int d = t & 1;
    if (t < KT - 1) asm volatile("s_waitcnt vmcnt(6)" ::: "memory");
    else            asm volatile("s_waitcnt vmcnt(0)" ::: "memory");
    __builtin_amdgcn_s_barrier();
    __builtin_amdgcn_sched_barrier(0);

    // ---- issue all 16 fragment reads (kk0 first)
    bf16x8 a0[4], b0[4], a1[4], b1[4];
#pragma unroll
    for (int m = 0; m < 4; ++m) {
      int r = wr * 64 + m * 16 + lr;
      a0[m] = *(const bf16x8*)(lA + d * 16384 + r * 128 + ((kg ^ (r & 7)) * 16));
    }
#pragma unroll
    for (int n = 0; n < 4; ++n) {
      int r = wc * 64 + n * 16 + lr;
      b0[n] = *(const bf16x8*)(lB + d * 32768 + r * 128 + ((kg ^ (r & 7)) * 16));
    }
#pragma unroll
    for (int m = 0; m < 4; ++m) {
      int r = wr * 64 + m * 16 + lr;
      a1[m] = *(const bf16x8*)(lA + d * 16384 + r * 128 + (((4 + kg) ^ (r & 7)) * 16));
    }
#pragma unroll
    for (int n = 0; n < 4; ++n) {
      int r = wc * 64 + n * 16 + lr;
      b1[n] = *(const bf16x8*)(lB + d * 32768 + r * 128 + (((4 + kg) ^ (r & 7)) * 16));
    }

    // ---- MFMA cluster kk0 (hw-waits only the first 8 reads)
    __builtin_amdgcn_s_setprio(1);
#pragma unroll
    for (int m = 0; m < 4; ++m)
#pragma unroll
      for (int n = 0; n < 4; ++n)
        acc[m][n] = __builtin_amdgcn_mfma_f32_16x16x32_bf16(a0[m], b0[n],
                                                            acc[m][n], 0, 0, 0);
    __builtin_amdgcn_s_setprio(0);

    // ---- all reads complete -> buf d free for tile t+2
    asm volatile("s_waitcnt lgkmcnt(0)" ::: "memory");
    __builtin_amdgcn_sched_barrier(0);
    __builtin_amdgcn_s_barrier();
    __builtin_amdgcn_sched_barrier(0);

    if (t + 2 < KT) {
      stageA(t + 2, d, 0); stageA(t + 2, d, 1);
      stageB(t + 2, d, 0); stageB(t + 2, d, 1);
      stageB(t + 2, d, 2); stageB(t + 2, d, 3);
    }

    // ---- MFMA cluster kk1
    __builtin_amdgcn_s_setprio(1);
#pragma unroll
    for (int m = 0; m < 4; ++m)
#pragma unroll
      for (int n = 0; n < 4; ++n)
        acc[m][n] = __builtin_amdgcn_mfma_f32_16x16x32_bf16(a1[m], b1[n],
                                                            acc[m][n], 0, 0, 0);
    __builtin_amdgcn_s_setprio(0);
  }

  // ---- epilogue: C/D layout col=lane&15, row=(lane>>4)*4+j [m89-verified]
  int rg = l >> 4;
#pragma unroll
  for (int m = 0; m < 4; ++m)
#pragma unroll
    for (int n = 0; n < 4; ++n)
#pragma unroll
      for (int j = 0; j < 4; ++j) {
        int row = e * CAP + mt * 128 + wr * 64 + m * 16 + rg * 4 + j;
        int col = nt * 256 + wc * 64 + n * 16 + lr;
        size_t off = (size_t)row * DM + col;
        float v = acc[m][n][j];
        if constexpr (SWI) {
          float u = (float)U[off];
          float s = u / (1.f + __expf(-u));
          C[off] = (__bf16)(s * v);            // h = silu(u) * v, in place
        } else {
          C[off] = (__bf16)v;
        }
      }
}

// --------------------------------------------- combine: y[tok] = sum w * ye
__global__ void combine_k(const __bf16* __restrict__ ye, const int* __restrict__ slot_dest,
                          const float* __restrict__ ew, float* __restrict__ out) {
  int tok = blockIdx.x;
  int c = threadIdx.x * 8;
  int d0 = slot_dest[2 * tok], d1 = slot_dest[2 * tok + 1];
  float w0 = ew[2 * tok], w1 = ew[2 * tok + 1];
  float r[8];
#pragma unroll
  for (int j = 0; j < 8; ++j) r[j] = 0.f;
  if (d0 >= 0) {
    bf16x8 y0 = *(const bf16x8*)(ye + (size_t)d0 * DM + c);
#pragma unroll
    for (int j = 0; j < 8; ++j) r[j] += w0 * (float)y0[j];
  }
  if (d1 >= 0) {
    bf16x8 y1 = *(const bf16x8*)(ye + (size_t)d1 * DM + c);
#pragma unroll
    for (int j = 0; j < 8; ++j) r[j] += w1 * (float)y1[j];
  }
  float* dst = out + (size_t)tok * DM + c;
  float4 o0; o0.x = r[0]; o0.y = r[1]; o0.z = r[2]; o0.w = r[3];
  float4 o1; o1.x = r[4]; o1.y = r[5]; o1.z = r[6]; o1.w = r[7];
  *(float4*)dst = o0;
  *(float4*)(dst + 4) = o1;
}

extern "C" void kernel_launch(void* const* d_in, const int* in_sizes, int n_in,
                              void* d_out, int out_size, void* d_ws, size_t ws_size,
                              hipStream_t stream) {
  const float* x  = (const float*)d_in[0];
  const float* ew = (const float*)d_in[1];
  const int*   ei = (const int*)d_in[2];
  const float* w1 = (const float*)d_in[3];
  const float* w2 = (const float*)d_in[4];
  const float* w3 = (const float*)d_in[5];
  float* out = (float*)d_out;
  char* ws = (char*)d_ws;

  const size_t SZ_MAT = (size_t)EC * DM * 2;            // 41,943,040 B
  __bf16* xg = (__bf16*)ws;                             // xg, then ye
  __bf16* uB = (__bf16*)(ws + SZ_MAT);                  // u, then h
  __bf16* wT = (__bf16*)(ws + 2 * SZ_MAT);              // [8][2048][2048] bf16
  char* ints = ws + 2 * SZ_MAT + (size_t)NEXP * DM * DM * 2;
  int* row_token = (int*)ints;
  int* slot_dest = row_token + EC;
  int* mcount    = slot_dest + NSLOT;

  dim3 tgrid(32, 32, NEXP);
  dim3 ggrid(8, 10, NEXP);                              // nt(256-wide), mt(128-tall), e

  route_k<<<1, 256, 0, stream>>>(ei, row_token, slot_dest, mcount, out);
  gather_k<<<EC, 256, 0, stream>>>(x, row_token, xg);

  transT_k<<<tgrid, 256, 0, stream>>>(w1, wT);
  gemm8_k<false><<<ggrid, 512, 0, stream>>>(xg, wT, uB, nullptr, mcount); // u

  transT_k<<<tgrid, 256, 0, stream>>>(w3, wT);
  gemm8_k<true><<<ggrid, 512, 0, stream>>>(xg, wT, uB, uB, mcount);       // h

  transT_k<<<tgrid, 256, 0, stream>>>(w2, wT);
  gemm8_k<false><<<ggrid, 512, 0, stream>>>(uB, wT, xg, nullptr, mcount); // ye

  combine_k<<<NTOK, 256, 0, stream>>>(xg, slot_dest, ew, out);
}